// Round 6
// baseline (819.211 us; speedup 1.0000x reference)
//
#include <hip/hip_runtime.h>
#include <math.h>

// Problem constants (from reference)
#define N_NODES 50000
#define IN_DIM  128
#define HIDDEN  64
#define OUT_DIM 10
#define HEADS   4
#define E_RAW   800000
#define E_TOT   (E_RAW + N_NODES)   // with self-loops: 850000
#define NEG_SLOPE 0.2f

#define NB_SCAN 196   // ceil(50000/256)
#define NB_EDGE 3321  // ceil(850000/256)
#define NB_GEMM 1563  // ceil(50000/32)

// ---------------- edge_index dtype detection ----------------
// flag[0] == 1  =>  int32 layout (shift 0);  flag[0] == 0  =>  int64 (shift 1).
__global__ void detect_i32(const int* __restrict__ ei, int* __restrict__ flag) {
    int t = threadIdx.x;                      // single block of 256
    int idx = 2 * (t * 3100 + 17) + 1;        // odd, < 1.6M for t < 256
    if (ei[idx] != 0) atomicOr(flag, 1);
}

// ---------------- CSR build ----------------

__global__ void zero_counts(int* __restrict__ counts, int* __restrict__ flag) {
    int i = blockIdx.x * 256 + threadIdx.x;
    if (i < N_NODES) counts[i] = 0;
    if (i == 0) flag[0] = 0;
}

__global__ void count_edges(const int* __restrict__ ei, int* __restrict__ counts,
                            const int* __restrict__ flag) {
    int t = blockIdx.x * 256 + threadIdx.x;
    if (t >= E_TOT) return;
    int sh = flag[0] ? 0 : 1;                 // int32 -> 0, int64 -> 1 (low word)
    int dst = (t < E_RAW) ? ei[(E_RAW + t) << sh] : (t - E_RAW);
    atomicAdd(&counts[dst], 1);
}

__global__ void scan1(const int* __restrict__ counts, int* __restrict__ indptr,
                      int* __restrict__ bsums) {
    __shared__ int sd[256];
    int t = threadIdx.x;
    int i = blockIdx.x * 256 + t;
    int v = (i < N_NODES) ? counts[i] : 0;
    sd[t] = v;
    __syncthreads();
    for (int o = 1; o < 256; o <<= 1) {
        int x = (t >= o) ? sd[t - o] : 0;
        __syncthreads();
        sd[t] += x;
        __syncthreads();
    }
    int incl = sd[t];
    if (i < N_NODES) indptr[i] = incl - v;   // block-local exclusive
    if (t == 255) bsums[blockIdx.x] = incl;  // block total
}

__global__ void scan2(int* __restrict__ bsums) {
    __shared__ int sd[256];
    int t = threadIdx.x;
    int v = (t < NB_SCAN) ? bsums[t] : 0;
    sd[t] = v;
    __syncthreads();
    for (int o = 1; o < 256; o <<= 1) {
        int x = (t >= o) ? sd[t - o] : 0;
        __syncthreads();
        sd[t] += x;
        __syncthreads();
    }
    if (t < NB_SCAN) bsums[t] = sd[t] - v;   // exclusive block offsets
}

__global__ void scan3(int* __restrict__ indptr, const int* __restrict__ bsums,
                      int* __restrict__ cursor) {
    int i = blockIdx.x * 256 + threadIdx.x;
    if (i < N_NODES) {
        int v = indptr[i] + bsums[blockIdx.x];
        indptr[i] = v;
        cursor[i] = v;
    }
    if (i == 0) indptr[N_NODES] = E_TOT;
}

__global__ void fill_edges(const int* __restrict__ ei, int* __restrict__ cursor,
                           int* __restrict__ esrc, const int* __restrict__ flag) {
    int t = blockIdx.x * 256 + threadIdx.x;
    if (t >= E_TOT) return;
    int sh = flag[0] ? 0 : 1;
    int src, dst;
    if (t < E_RAW) { src = ei[t << sh]; dst = ei[(E_RAW + t) << sh]; }
    else           { src = t - E_RAW; dst = src; }
    int pos = atomicAdd(&cursor[dst], 1);
    esrc[pos] = src;
}

// ---------------- GEMM + attention logits (register-tiled) ----------------
// Tile: 32 rows x 256 cols per block of 256 threads.
// Thread (da2 = t&31, rg = t>>5) owns rows rg*4..+3 and cols
// {h*64 + da2*2, h*64 + da2*2+1 : h=0..3}  (2 dims x 4 heads = 8 cols).
// Per k: 4 LDS broadcasts (x) + 4 float2 global loads (W, L2-resident) + 32 FMA.
// H stored DIM-MAJOR: H[n*256 + d*4 + h] -> thread's 8 values per row are the
// 8 contiguous floats at d0*4 -> two adjacent dwordx4 stores, no LDS round-trip.
// AL via 5-stage butterfly over the 32 lanes of each wave-half (one row-group
// per half; da2 spans 0..31 in each half).
template <int K>
__global__ void __launch_bounds__(256) gemm_al(
    const float* __restrict__ X, const float* __restrict__ W,
    const float* __restrict__ asrc, const float* __restrict__ adst,
    float* __restrict__ H, float* __restrict__ AL) {
    __shared__ float xs[32 * K];
    int t = threadIdx.x;
    int n0 = blockIdx.x * 32;

    // stage X tile (32 rows x K), float4-vectorized, clamp tail rows
    const int K4 = K / 4;
    const float4* X4 = (const float4*)X;
    float4* xs4 = (float4*)xs;
    for (int i4 = t; i4 < 32 * K4; i4 += 256) {
        int r = i4 / K4, kk = i4 % K4;       // K4 = 32 or 16 (power of 2)
        int n = n0 + r; if (n >= N_NODES) n = N_NODES - 1;
        xs4[i4] = X4[(size_t)n * K4 + kk];
    }
    __syncthreads();

    int da2 = t & 31;          // dim pair index: d0 = da2*2
    int rg  = t >> 5;          // row group: r0 = rg*4
    int d0 = da2 * 2;
    int r0 = rg * 4;

    float acc[4][8];
#pragma unroll
    for (int i = 0; i < 4; i++)
#pragma unroll
        for (int j = 0; j < 8; j++) acc[i][j] = 0.f;

    const float2* W2 = (const float2*)W;   // W[k][c], c = h*64 + d
#pragma unroll 4
    for (int k = 0; k < K; k++) {
        float x0 = xs[(r0 + 0) * K + k];
        float x1 = xs[(r0 + 1) * K + k];
        float x2 = xs[(r0 + 2) * K + k];
        float x3 = xs[(r0 + 3) * K + k];
#pragma unroll
        for (int h = 0; h < 4; h++) {
            float2 w = W2[k * 128 + h * 32 + da2];
            acc[0][2*h] += x0 * w.x; acc[0][2*h+1] += x0 * w.y;
            acc[1][2*h] += x1 * w.x; acc[1][2*h+1] += x1 * w.y;
            acc[2][2*h] += x2 * w.x; acc[2][2*h+1] += x2 * w.y;
            acc[3][2*h] += x3 * w.x; acc[3][2*h+1] += x3 * w.y;
        }
    }

    // H store: dim-major, 8 contiguous floats per row at d0*4
#pragma unroll
    for (int i = 0; i < 4; i++) {
        int n = n0 + r0 + i;
        if (n < N_NODES) {
            float4 v0 = make_float4(acc[i][0], acc[i][2], acc[i][4], acc[i][6]);
            float4 v1 = make_float4(acc[i][1], acc[i][3], acc[i][5], acc[i][7]);
            float4* Hp = (float4*)(H + (size_t)n * 256 + d0 * 4);
            Hp[0] = v0;   // dim d0,   heads 0..3
            Hp[1] = v1;   // dim d0+1, heads 0..3
        }
    }

    // AL: per-row per-head dot with asrc/adst, butterfly over 32-lane half
    const float2* as2 = (const float2*)asrc;
    const float2* ad2 = (const float2*)adst;
    float sp[4][4], dp[4][4];
#pragma unroll
    for (int h = 0; h < 4; h++) {
        float2 av = as2[h * 32 + da2];
        float2 dv = ad2[h * 32 + da2];
#pragma unroll
        for (int i = 0; i < 4; i++) {
            sp[i][h] = acc[i][2*h] * av.x + acc[i][2*h+1] * av.y;
            dp[i][h] = acc[i][2*h] * dv.x + acc[i][2*h+1] * dv.y;
        }
    }
#pragma unroll
    for (int o = 1; o < 32; o <<= 1) {
#pragma unroll
        for (int i = 0; i < 4; i++)
#pragma unroll
            for (int h = 0; h < 4; h++) {
                sp[i][h] += __shfl_xor(sp[i][h], o, 64);
                dp[i][h] += __shfl_xor(dp[i][h], o, 64);
            }
    }
    if (da2 == 0) {
#pragma unroll
        for (int i = 0; i < 4; i++) {
            int n = n0 + r0 + i;
            if (n < N_NODES) {
#pragma unroll
                for (int h = 0; h < 4; h++) {
                    AL[n * 8 + h]     = sp[i][h];
                    AL[n * 8 + 4 + h] = dp[i][h];
                }
            }
        }
    }
}

// ---------------- Per-destination softmax + aggregation ----------------
// One wave per dst node, single pass (no max shift; logits analytically
// bounded — validated end-to-end rounds 4/5). Chunked: stage 64 edge ids
// per coalesced load, shfl-broadcast; unroll 2 so two edges' AL/H gathers
// are in flight together. Lane owns dim=lane; H read = one dwordx4.
__global__ void __launch_bounds__(256) aggregate(
    const float* __restrict__ H, const float* __restrict__ AL,
    const int* __restrict__ indptr, const int* __restrict__ esrc,
    const float* __restrict__ bias, float* __restrict__ XOUT) {
    int wave = threadIdx.x >> 6, lane = threadIdx.x & 63;
    int n = blockIdx.x * 4 + wave;   // 12500 * 4 == 50000 exactly

    int start = indptr[n], end = indptr[n + 1];
    const float4* AL4 = (const float4*)AL;
    const float4* H4  = (const float4*)H;
    float4 ald = AL4[n * 2 + 1];

    float d0 = 0.f, d1 = 0.f, d2 = 0.f, d3 = 0.f;
    float a0 = 0.f, a1 = 0.f, a2 = 0.f, a3 = 0.f;

    for (int cb = start; cb < end; cb += 64) {
        int cnt = end - cb; if (cnt > 64) cnt = 64;
        int my_s = (lane < cnt) ? esrc[cb + lane] : 0;
#pragma unroll 2
        for (int rel = 0; rel < cnt; rel++) {
            int s = __shfl(my_s, rel, 64);
            float4 as = AL4[s * 2];
            float4 h  = H4[(s << 6) + lane];
            float v0 = as.x + ald.x; v0 = fmaxf(v0, NEG_SLOPE * v0);
            float v1 = as.y + ald.y; v1 = fmaxf(v1, NEG_SLOPE * v1);
            float v2 = as.z + ald.z; v2 = fmaxf(v2, NEG_SLOPE * v2);
            float v3 = as.w + ald.w; v3 = fmaxf(v3, NEG_SLOPE * v3);
            float e0 = __expf(v0); float e1 = __expf(v1);
            float e2 = __expf(v2); float e3 = __expf(v3);
            d0 += e0; d1 += e1; d2 += e2; d3 += e3;
            a0 += e0 * h.x;
            a1 += e1 * h.y;
            a2 += e2 * h.z;
            a3 += e3 * h.w;
        }
    }

    float r = a0 / d0 + a1 / d1 + a2 / d2 + a3 / d3;
    r = 0.25f * r + bias[lane];
    r = r > 0.f ? r : (__expf(r) - 1.f);   // ELU
    XOUT[n * 64 + lane] = r;
}

// ---------------- Final FC ----------------
__global__ void __launch_bounds__(256) fc_kernel(
    const float* __restrict__ X, const float* __restrict__ fcW,
    const float* __restrict__ fcb, float* __restrict__ OUT) {
    __shared__ float ws[64 * 10];
    __shared__ float bs[10];
    int t = threadIdx.x;
    for (int i = t; i < 640; i += 256) ws[i] = fcW[i];   // 640 > blockDim
    if (t < 10) bs[t] = fcb[t];
    __syncthreads();
    int n = blockIdx.x * 256 + t;
    if (n >= N_NODES) return;
    float acc[10];
#pragma unroll
    for (int c = 0; c < 10; c++) acc[c] = bs[c];
    for (int d = 0; d < 64; d++) {
        float x = X[n * 64 + d];
#pragma unroll
        for (int c = 0; c < 10; c++) acc[c] += x * ws[d * 10 + c];
    }
#pragma unroll
    for (int c = 0; c < 10; c++) OUT[n * 10 + c] = acc[c];
}

// ---------------- Launch ----------------
extern "C" void kernel_launch(void* const* d_in, const int* in_sizes, int n_in,
                              void* d_out, int out_size, void* d_ws, size_t ws_size,
                              hipStream_t stream) {
    const float* x     = (const float*)d_in[0];
    const int*   ei    = (const int*)d_in[1];
    const float* W[3]    = {(const float*)d_in[2], (const float*)d_in[6], (const float*)d_in[10]};
    const float* asrc[3] = {(const float*)d_in[3], (const float*)d_in[7], (const float*)d_in[11]};
    const float* adst[3] = {(const float*)d_in[4], (const float*)d_in[8], (const float*)d_in[12]};
    const float* bias[3] = {(const float*)d_in[5], (const float*)d_in[9], (const float*)d_in[13]};
    const float* fcW = (const float*)d_in[14];
    const float* fcb = (const float*)d_in[15];
    float* out = (float*)d_out;

    char* ws = (char*)d_ws;
    size_t off = 0;
    auto alloc = [&](size_t bytes) {
        void* p = ws + off;
        off = (off + bytes + 255) & ~(size_t)255;
        return p;
    };
    float* H      = (float*)alloc((size_t)N_NODES * 256 * 4);   // 51.2 MB
    float* AL     = (float*)alloc((size_t)N_NODES * 8 * 4);     // 1.6 MB
    float* XA     = (float*)alloc((size_t)N_NODES * 64 * 4);    // 12.8 MB
    float* XB     = (float*)alloc((size_t)N_NODES * 64 * 4);    // 12.8 MB
    int*   counts = (int*)alloc((size_t)N_NODES * 4);
    int*   indptr = (int*)alloc((size_t)(N_NODES + 1) * 4);
    int*   cursor = (int*)alloc((size_t)N_NODES * 4);
    int*   esrc   = (int*)alloc((size_t)E_TOT * 4);             // 3.4 MB
    int*   bsums  = (int*)alloc(256 * 4);
    int*   flag   = (int*)alloc(256 * 4);

    // CSR build (graph is identical each call; ws is re-poisoned so rebuild)
    zero_counts<<<NB_SCAN, 256, 0, stream>>>(counts, flag);
    detect_i32<<<1, 256, 0, stream>>>(ei, flag);
    count_edges<<<NB_EDGE, 256, 0, stream>>>(ei, counts, flag);
    scan1<<<NB_SCAN, 256, 0, stream>>>(counts, indptr, bsums);
    scan2<<<1, 256, 0, stream>>>(bsums);
    scan3<<<NB_SCAN, 256, 0, stream>>>(indptr, bsums, cursor);
    fill_edges<<<NB_EDGE, 256, 0, stream>>>(ei, cursor, esrc, flag);

    // Layer 0
    gemm_al<128><<<NB_GEMM, 256, 0, stream>>>(x, W[0], asrc[0], adst[0], H, AL);
    aggregate<<<N_NODES / 4, 256, 0, stream>>>(H, AL, indptr, esrc, bias[0], XA);
    // Layer 1
    gemm_al<64><<<NB_GEMM, 256, 0, stream>>>(XA, W[1], asrc[1], adst[1], H, AL);
    aggregate<<<N_NODES / 4, 256, 0, stream>>>(H, AL, indptr, esrc, bias[1], XB);
    // Layer 2
    gemm_al<64><<<NB_GEMM, 256, 0, stream>>>(XB, W[2], asrc[2], adst[2], H, AL);
    aggregate<<<N_NODES / 4, 256, 0, stream>>>(H, AL, indptr, esrc, bias[2], XA);

    // Final FC
    fc_kernel<<<NB_SCAN, 256, 0, stream>>>(XA, fcW, fcb, out);
}

// Round 7
// 739.916 us; speedup vs baseline: 1.1072x; 1.1072x over previous
//
#include <hip/hip_runtime.h>
#include <math.h>

// Problem constants (from reference)
#define N_NODES 50000
#define IN_DIM  128
#define HIDDEN  64
#define OUT_DIM 10
#define HEADS   4
#define E_RAW   800000
#define E_TOT   (E_RAW + N_NODES)   // with self-loops: 850000
#define NEG_SLOPE 0.2f

#define NB_SCAN 196   // ceil(50000/256)
#define NB_EDGE 3321  // ceil(850000/256)
#define NB_GEMM 1563  // ceil(50000/32)

// ---------------- edge_index dtype detection ----------------
// flag[0] == 1  =>  int32 layout (shift 0);  flag[0] == 0  =>  int64 (shift 1).
__global__ void detect_i32(const int* __restrict__ ei, int* __restrict__ flag) {
    int t = threadIdx.x;                      // single block of 256
    int idx = 2 * (t * 3100 + 17) + 1;        // odd, < 1.6M for t < 256
    if (ei[idx] != 0) atomicOr(flag, 1);
}

// ---------------- CSR build ----------------

__global__ void zero_counts(int* __restrict__ counts, int* __restrict__ flag) {
    int i = blockIdx.x * 256 + threadIdx.x;
    if (i < N_NODES) counts[i] = 0;
    if (i == 0) flag[0] = 0;
}

__global__ void count_edges(const int* __restrict__ ei, int* __restrict__ counts,
                            const int* __restrict__ flag) {
    int t = blockIdx.x * 256 + threadIdx.x;
    if (t >= E_TOT) return;
    int sh = flag[0] ? 0 : 1;                 // int32 -> 0, int64 -> 1 (low word)
    int dst = (t < E_RAW) ? ei[(E_RAW + t) << sh] : (t - E_RAW);
    atomicAdd(&counts[dst], 1);
}

__global__ void scan1(const int* __restrict__ counts, int* __restrict__ indptr,
                      int* __restrict__ bsums) {
    __shared__ int sd[256];
    int t = threadIdx.x;
    int i = blockIdx.x * 256 + t;
    int v = (i < N_NODES) ? counts[i] : 0;
    sd[t] = v;
    __syncthreads();
    for (int o = 1; o < 256; o <<= 1) {
        int x = (t >= o) ? sd[t - o] : 0;
        __syncthreads();
        sd[t] += x;
        __syncthreads();
    }
    int incl = sd[t];
    if (i < N_NODES) indptr[i] = incl - v;   // block-local exclusive
    if (t == 255) bsums[blockIdx.x] = incl;  // block total
}

__global__ void scan2(int* __restrict__ bsums) {
    __shared__ int sd[256];
    int t = threadIdx.x;
    int v = (t < NB_SCAN) ? bsums[t] : 0;
    sd[t] = v;
    __syncthreads();
    for (int o = 1; o < 256; o <<= 1) {
        int x = (t >= o) ? sd[t - o] : 0;
        __syncthreads();
        sd[t] += x;
        __syncthreads();
    }
    if (t < NB_SCAN) bsums[t] = sd[t] - v;   // exclusive block offsets
}

__global__ void scan3(int* __restrict__ indptr, const int* __restrict__ bsums,
                      int* __restrict__ cursor) {
    int i = blockIdx.x * 256 + threadIdx.x;
    if (i < N_NODES) {
        int v = indptr[i] + bsums[blockIdx.x];
        indptr[i] = v;
        cursor[i] = v;
    }
    if (i == 0) indptr[N_NODES] = E_TOT;
}

__global__ void fill_edges(const int* __restrict__ ei, int* __restrict__ cursor,
                           int* __restrict__ esrc, const int* __restrict__ flag) {
    int t = blockIdx.x * 256 + threadIdx.x;
    if (t >= E_TOT) return;
    int sh = flag[0] ? 0 : 1;
    int src, dst;
    if (t < E_RAW) { src = ei[t << sh]; dst = ei[(E_RAW + t) << sh]; }
    else           { src = t - E_RAW; dst = src; }
    int pos = atomicAdd(&cursor[dst], 1);
    esrc[pos] = src;
}

// ---------------- GEMM + attention logits (W via LDS chunks) ----------------
// Tile: 32 rows x 256 cols per 256-thread block; thread (da2=t&31, rg=t>>5)
// owns rows rg*4..+3 and cols {h*64 + da2*2 +0,1 : h}.
// X tile stored TRANSPOSED in LDS (xs_t[k][row]) -> the 4 row-operands per k
// are one ds_read_b128 (broadcast across the 32 lanes of a half-wave).
// W staged in LDS 32 k-rows at a time (32 KB) by cooperative dwordx4 loads;
// inner loop reads it as conflict-free ds_read_b64 (consecutive float2/lane).
// Per k: 1 b128 + 4 b64 LDS + 32 FMA -> VALU-bound.
template <int K>
__global__ void __launch_bounds__(256) gemm_al(
    const float* __restrict__ X, const float* __restrict__ W,
    const float* __restrict__ asrc, const float* __restrict__ adst,
    float* __restrict__ H, float* __restrict__ AL) {
    __shared__ float xs_t[K * 32];      // [k][row]
    __shared__ float wsh[32 * 256];     // one 32-k chunk of W
    int t = threadIdx.x;
    int n0 = blockIdx.x * 32;

    // stage X tile transposed: thread reads float4 along k, scatters 4 b32
    const int K4 = K / 4;
    const float4* X4 = (const float4*)X;
    for (int idx = t; idx < 32 * K4; idx += 256) {
        int r = idx / K4, k4 = idx % K4;
        int n = n0 + r; if (n >= N_NODES) n = N_NODES - 1;
        float4 v = X4[(size_t)n * K4 + k4];
        xs_t[(4 * k4 + 0) * 32 + r] = v.x;
        xs_t[(4 * k4 + 1) * 32 + r] = v.y;
        xs_t[(4 * k4 + 2) * 32 + r] = v.z;
        xs_t[(4 * k4 + 3) * 32 + r] = v.w;
    }

    int da2 = t & 31;          // dim pair: d0 = da2*2
    int rg  = t >> 5;          // row group: r0 = rg*4
    int d0 = da2 * 2;
    int r0 = rg * 4;

    float acc[4][8];
#pragma unroll
    for (int i = 0; i < 4; i++)
#pragma unroll
        for (int j = 0; j < 8; j++) acc[i][j] = 0.f;

    float4* wsh4 = (float4*)wsh;
    const float2* wsh2 = (const float2*)wsh;
    for (int kb = 0; kb < K; kb += 32) {
        __syncthreads();   // xs_t ready (1st iter) / wsh consumed (later iters)
        const float4* Wc = (const float4*)(W + kb * 256);
        for (int i = t; i < 2048; i += 256) wsh4[i] = Wc[i];
        __syncthreads();
#pragma unroll 4
        for (int k = 0; k < 32; k++) {
            float4 xv = *(const float4*)&xs_t[(kb + k) * 32 + r0];
#pragma unroll
            for (int h = 0; h < 4; h++) {
                float2 w = wsh2[k * 128 + h * 32 + da2];
                acc[0][2*h] += xv.x * w.x; acc[0][2*h+1] += xv.x * w.y;
                acc[1][2*h] += xv.y * w.x; acc[1][2*h+1] += xv.y * w.y;
                acc[2][2*h] += xv.z * w.x; acc[2][2*h+1] += xv.z * w.y;
                acc[3][2*h] += xv.w * w.x; acc[3][2*h+1] += xv.w * w.y;
            }
        }
    }

    // H store: dim-major H[n*256 + d*4 + h]; thread's 8 values per row are
    // the 8 contiguous floats at d0*4 -> two adjacent dwordx4 stores.
#pragma unroll
    for (int i = 0; i < 4; i++) {
        int n = n0 + r0 + i;
        if (n < N_NODES) {
            float4 v0 = make_float4(acc[i][0], acc[i][2], acc[i][4], acc[i][6]);
            float4 v1 = make_float4(acc[i][1], acc[i][3], acc[i][5], acc[i][7]);
            float4* Hp = (float4*)(H + (size_t)n * 256 + d0 * 4);
            Hp[0] = v0;   // dim d0,   heads 0..3
            Hp[1] = v1;   // dim d0+1, heads 0..3
        }
    }

    // AL: per-row per-head dot with asrc/adst, butterfly over 32-lane half
    const float2* as2 = (const float2*)asrc;
    const float2* ad2 = (const float2*)adst;
    float sp[4][4], dp[4][4];
#pragma unroll
    for (int h = 0; h < 4; h++) {
        float2 av = as2[h * 32 + da2];
        float2 dv = ad2[h * 32 + da2];
#pragma unroll
        for (int i = 0; i < 4; i++) {
            sp[i][h] = acc[i][2*h] * av.x + acc[i][2*h+1] * av.y;
            dp[i][h] = acc[i][2*h] * dv.x + acc[i][2*h+1] * dv.y;
        }
    }
#pragma unroll
    for (int o = 1; o < 32; o <<= 1) {
#pragma unroll
        for (int i = 0; i < 4; i++)
#pragma unroll
            for (int h = 0; h < 4; h++) {
                sp[i][h] += __shfl_xor(sp[i][h], o, 64);
                dp[i][h] += __shfl_xor(dp[i][h], o, 64);
            }
    }
    if (da2 == 0) {
#pragma unroll
        for (int i = 0; i < 4; i++) {
            int n = n0 + r0 + i;
            if (n < N_NODES) {
#pragma unroll
                for (int h = 0; h < 4; h++) {
                    AL[n * 8 + h]     = sp[i][h];
                    AL[n * 8 + 4 + h] = dp[i][h];
                }
            }
        }
    }
}

// ---------------- Per-destination softmax + aggregation ----------------
// One wave per dst node, single pass (no max shift; logits analytically
// bounded — validated end-to-end rounds 4-6). Depth-4 pipeline: 4 edges'
// AL+H loads (8 independent global loads) issued back-to-back, then compute.
// Tail uses wave-uniform branches (m uniform -> s_cbranch, no divergence).
__global__ void __launch_bounds__(256) aggregate(
    const float* __restrict__ H, const float* __restrict__ AL,
    const int* __restrict__ indptr, const int* __restrict__ esrc,
    const float* __restrict__ bias, float* __restrict__ XOUT) {
    int wave = threadIdx.x >> 6, lane = threadIdx.x & 63;
    int n = blockIdx.x * 4 + wave;   // 12500 * 4 == 50000 exactly

    int start = indptr[n], end = indptr[n + 1];
    const float4* AL4 = (const float4*)AL;
    const float4* H4  = (const float4*)H;
    float4 ald = AL4[n * 2 + 1];

    float d0 = 0.f, d1 = 0.f, d2 = 0.f, d3 = 0.f;
    float a0 = 0.f, a1 = 0.f, a2 = 0.f, a3 = 0.f;

#define EDGE_BODY(A, Hh)                                            \
    {                                                               \
        float v0 = A.x + ald.x; v0 = fmaxf(v0, NEG_SLOPE * v0);     \
        float v1 = A.y + ald.y; v1 = fmaxf(v1, NEG_SLOPE * v1);     \
        float v2 = A.z + ald.z; v2 = fmaxf(v2, NEG_SLOPE * v2);     \
        float v3 = A.w + ald.w; v3 = fmaxf(v3, NEG_SLOPE * v3);     \
        float e0 = __expf(v0), e1 = __expf(v1);                     \
        float e2 = __expf(v2), e3 = __expf(v3);                     \
        d0 += e0; d1 += e1; d2 += e2; d3 += e3;                     \
        a0 += e0 * Hh.x; a1 += e1 * Hh.y;                           \
        a2 += e2 * Hh.z; a3 += e3 * Hh.w;                           \
    }

    for (int cb = start; cb < end; cb += 64) {
        int cnt = end - cb; if (cnt > 64) cnt = 64;
        int my_s = (lane < cnt) ? esrc[cb + lane] : 0;
        for (int base = 0; base < cnt; base += 4) {
            int m = cnt - base;   // wave-uniform
            int s0 = __shfl(my_s, base, 64);
            int s1 = __shfl(my_s, base + (1 < m ? 1 : 0), 64);
            int s2 = __shfl(my_s, base + (2 < m ? 2 : 0), 64);
            int s3 = __shfl(my_s, base + (3 < m ? 3 : 0), 64);
            float4 A0 = AL4[s0 * 2];
            float4 A1 = AL4[s1 * 2];
            float4 A2 = AL4[s2 * 2];
            float4 A3 = AL4[s3 * 2];
            float4 H0 = H4[(s0 << 6) + lane];
            float4 H1 = H4[(s1 << 6) + lane];
            float4 H2 = H4[(s2 << 6) + lane];
            float4 H3 = H4[(s3 << 6) + lane];
            EDGE_BODY(A0, H0);
            if (m > 1) EDGE_BODY(A1, H1);
            if (m > 2) EDGE_BODY(A2, H2);
            if (m > 3) EDGE_BODY(A3, H3);
        }
    }
#undef EDGE_BODY

    float r = a0 / d0 + a1 / d1 + a2 / d2 + a3 / d3;
    r = 0.25f * r + bias[lane];
    r = r > 0.f ? r : (__expf(r) - 1.f);   // ELU
    XOUT[n * 64 + lane] = r;
}

// ---------------- Final FC ----------------
__global__ void __launch_bounds__(256) fc_kernel(
    const float* __restrict__ X, const float* __restrict__ fcW,
    const float* __restrict__ fcb, float* __restrict__ OUT) {
    __shared__ float ws[64 * 10];
    __shared__ float bs[10];
    int t = threadIdx.x;
    for (int i = t; i < 640; i += 256) ws[i] = fcW[i];   // 640 > blockDim
    if (t < 10) bs[t] = fcb[t];
    __syncthreads();
    int n = blockIdx.x * 256 + t;
    if (n >= N_NODES) return;
    float acc[10];
#pragma unroll
    for (int c = 0; c < 10; c++) acc[c] = bs[c];
    for (int d = 0; d < 64; d++) {
        float x = X[n * 64 + d];
#pragma unroll
        for (int c = 0; c < 10; c++) acc[c] += x * ws[d * 10 + c];
    }
#pragma unroll
    for (int c = 0; c < 10; c++) OUT[n * 10 + c] = acc[c];
}

// ---------------- Launch ----------------
extern "C" void kernel_launch(void* const* d_in, const int* in_sizes, int n_in,
                              void* d_out, int out_size, void* d_ws, size_t ws_size,
                              hipStream_t stream) {
    const float* x     = (const float*)d_in[0];
    const int*   ei    = (const int*)d_in[1];
    const float* W[3]    = {(const float*)d_in[2], (const float*)d_in[6], (const float*)d_in[10]};
    const float* asrc[3] = {(const float*)d_in[3], (const float*)d_in[7], (const float*)d_in[11]};
    const float* adst[3] = {(const float*)d_in[4], (const float*)d_in[8], (const float*)d_in[12]};
    const float* bias[3] = {(const float*)d_in[5], (const float*)d_in[9], (const float*)d_in[13]};
    const float* fcW = (const float*)d_in[14];
    const float* fcb = (const float*)d_in[15];
    float* out = (float*)d_out;

    char* ws = (char*)d_ws;
    size_t off = 0;
    auto alloc = [&](size_t bytes) {
        void* p = ws + off;
        off = (off + bytes + 255) & ~(size_t)255;
        return p;
    };
    float* H      = (float*)alloc((size_t)N_NODES * 256 * 4);   // 51.2 MB
    float* AL     = (float*)alloc((size_t)N_NODES * 8 * 4);     // 1.6 MB
    float* XA     = (float*)alloc((size_t)N_NODES * 64 * 4);    // 12.8 MB
    float* XB     = (float*)alloc((size_t)N_NODES * 64 * 4);    // 12.8 MB
    int*   counts = (int*)alloc((size_t)N_NODES * 4);
    int*   indptr = (int*)alloc((size_t)(N_NODES + 1) * 4);
    int*   cursor = (int*)alloc((size_t)N_NODES * 4);
    int*   esrc   = (int*)alloc((size_t)E_TOT * 4);             // 3.4 MB
    int*   bsums  = (int*)alloc(256 * 4);
    int*   flag   = (int*)alloc(256 * 4);

    // CSR build (graph is identical each call; ws is re-poisoned so rebuild)
    zero_counts<<<NB_SCAN, 256, 0, stream>>>(counts, flag);
    detect_i32<<<1, 256, 0, stream>>>(ei, flag);
    count_edges<<<NB_EDGE, 256, 0, stream>>>(ei, counts, flag);
    scan1<<<NB_SCAN, 256, 0, stream>>>(counts, indptr, bsums);
    scan2<<<1, 256, 0, stream>>>(bsums);
    scan3<<<NB_SCAN, 256, 0, stream>>>(indptr, bsums, cursor);
    fill_edges<<<NB_EDGE, 256, 0, stream>>>(ei, cursor, esrc, flag);

    // Layer 0
    gemm_al<128><<<NB_GEMM, 256, 0, stream>>>(x, W[0], asrc[0], adst[0], H, AL);
    aggregate<<<N_NODES / 4, 256, 0, stream>>>(H, AL, indptr, esrc, bias[0], XA);
    // Layer 1
    gemm_al<64><<<NB_GEMM, 256, 0, stream>>>(XA, W[1], asrc[1], adst[1], H, AL);
    aggregate<<<N_NODES / 4, 256, 0, stream>>>(H, AL, indptr, esrc, bias[1], XB);
    // Layer 2
    gemm_al<64><<<NB_GEMM, 256, 0, stream>>>(XB, W[2], asrc[2], adst[2], H, AL);
    aggregate<<<N_NODES / 4, 256, 0, stream>>>(H, AL, indptr, esrc, bias[2], XA);

    // Final FC
    fc_kernel<<<NB_SCAN, 256, 0, stream>>>(XA, fcW, fcb, out);
}

// Round 8
// 578.788 us; speedup vs baseline: 1.4154x; 1.2784x over previous
//
#include <hip/hip_runtime.h>
#include <hip/hip_fp16.h>
#include <math.h>

// Problem constants (from reference)
#define N_NODES 50000
#define IN_DIM  128
#define HIDDEN  64
#define OUT_DIM 10
#define HEADS   4
#define E_RAW   800000
#define E_TOT   (E_RAW + N_NODES)   // with self-loops: 850000
#define NEG_SLOPE 0.2f

#define NB_SCAN 196   // ceil(50000/256)
#define NB_EDGE 3321  // ceil(850000/256)
#define NB_GEMM 1563  // ceil(50000/32)

// ---------------- edge_index dtype detection ----------------
// flag[0] == 1  =>  int32 layout (shift 0);  flag[0] == 0  =>  int64 (shift 1).
__global__ void detect_i32(const int* __restrict__ ei, int* __restrict__ flag) {
    int t = threadIdx.x;                      // single block of 256
    int idx = 2 * (t * 3100 + 17) + 1;        // odd, < 1.6M for t < 256
    if (ei[idx] != 0) atomicOr(flag, 1);
}

// ---------------- CSR build ----------------

__global__ void zero_counts(int* __restrict__ counts, int* __restrict__ flag) {
    int i = blockIdx.x * 256 + threadIdx.x;
    if (i < N_NODES) counts[i] = 0;
    if (i == 0) flag[0] = 0;
}

__global__ void count_edges(const int* __restrict__ ei, int* __restrict__ counts,
                            const int* __restrict__ flag) {
    int t = blockIdx.x * 256 + threadIdx.x;
    if (t >= E_TOT) return;
    int sh = flag[0] ? 0 : 1;                 // int32 -> 0, int64 -> 1 (low word)
    int dst = (t < E_RAW) ? ei[(E_RAW + t) << sh] : (t - E_RAW);
    atomicAdd(&counts[dst], 1);
}

__global__ void scan1(const int* __restrict__ counts, int* __restrict__ indptr,
                      int* __restrict__ bsums) {
    __shared__ int sd[256];
    int t = threadIdx.x;
    int i = blockIdx.x * 256 + t;
    int v = (i < N_NODES) ? counts[i] : 0;
    sd[t] = v;
    __syncthreads();
    for (int o = 1; o < 256; o <<= 1) {
        int x = (t >= o) ? sd[t - o] : 0;
        __syncthreads();
        sd[t] += x;
        __syncthreads();
    }
    int incl = sd[t];
    if (i < N_NODES) indptr[i] = incl - v;   // block-local exclusive
    if (t == 255) bsums[blockIdx.x] = incl;  // block total
}

__global__ void scan2(int* __restrict__ bsums) {
    __shared__ int sd[256];
    int t = threadIdx.x;
    int v = (t < NB_SCAN) ? bsums[t] : 0;
    sd[t] = v;
    __syncthreads();
    for (int o = 1; o < 256; o <<= 1) {
        int x = (t >= o) ? sd[t - o] : 0;
        __syncthreads();
        sd[t] += x;
        __syncthreads();
    }
    if (t < NB_SCAN) bsums[t] = sd[t] - v;   // exclusive block offsets
}

__global__ void scan3(int* __restrict__ indptr, const int* __restrict__ bsums,
                      int* __restrict__ cursor) {
    int i = blockIdx.x * 256 + threadIdx.x;
    if (i < N_NODES) {
        int v = indptr[i] + bsums[blockIdx.x];
        indptr[i] = v;
        cursor[i] = v;
    }
    if (i == 0) indptr[N_NODES] = E_TOT;
}

__global__ void fill_edges(const int* __restrict__ ei, int* __restrict__ cursor,
                           int* __restrict__ esrc, const int* __restrict__ flag) {
    int t = blockIdx.x * 256 + threadIdx.x;
    if (t >= E_TOT) return;
    int sh = flag[0] ? 0 : 1;
    int src, dst;
    if (t < E_RAW) { src = ei[t << sh]; dst = ei[(E_RAW + t) << sh]; }
    else           { src = t - E_RAW; dst = src; }
    int pos = atomicAdd(&cursor[dst], 1);
    esrc[pos] = src;
}

// ---------------- GEMM + attention logits (W via LDS chunks) ----------------
// Tile: 32 rows x 256 cols per 256-thread block; thread (da2=t&31, rg=t>>5)
// owns rows rg*4..+3 and cols {h*64 + da2*2 +0,1 : h}.
// X tile TRANSPOSED in LDS (xs_t[k][row]); W staged 16 k-rows (16 KB) at a
// time -> total LDS 32 KB (K=128) / 24 KB (K=64) -> 5-6 blocks/CU.
// H stored DIM-MAJOR as FP16: H[n*256 + d*4 + h] halfs; thread's 8 values
// per row = 8 contiguous halfs = one 16 B store.
template <int K>
__global__ void __launch_bounds__(256) gemm_al(
    const float* __restrict__ X, const float* __restrict__ W,
    const float* __restrict__ asrc, const float* __restrict__ adst,
    __half* __restrict__ H, float* __restrict__ AL) {
    __shared__ float xs_t[K * 32];      // [k][row]
    __shared__ float wsh[16 * 256];     // one 16-k chunk of W
    int t = threadIdx.x;
    int n0 = blockIdx.x * 32;

    // stage X tile transposed: thread reads float4 along k, scatters 4 b32
    const int K4 = K / 4;
    const float4* X4 = (const float4*)X;
    for (int idx = t; idx < 32 * K4; idx += 256) {
        int r = idx / K4, k4 = idx % K4;
        int n = n0 + r; if (n >= N_NODES) n = N_NODES - 1;
        float4 v = X4[(size_t)n * K4 + k4];
        xs_t[(4 * k4 + 0) * 32 + r] = v.x;
        xs_t[(4 * k4 + 1) * 32 + r] = v.y;
        xs_t[(4 * k4 + 2) * 32 + r] = v.z;
        xs_t[(4 * k4 + 3) * 32 + r] = v.w;
    }

    int da2 = t & 31;          // dim pair: d0 = da2*2
    int rg  = t >> 5;          // row group: r0 = rg*4
    int d0 = da2 * 2;
    int r0 = rg * 4;

    float acc[4][8];
#pragma unroll
    for (int i = 0; i < 4; i++)
#pragma unroll
        for (int j = 0; j < 8; j++) acc[i][j] = 0.f;

    float4* wsh4 = (float4*)wsh;
    const float2* wsh2 = (const float2*)wsh;
    for (int kb = 0; kb < K; kb += 16) {
        __syncthreads();   // xs_t ready (1st iter) / wsh consumed (later)
        const float4* Wc = (const float4*)(W + kb * 256);
        for (int i = t; i < 1024; i += 256) wsh4[i] = Wc[i];
        __syncthreads();
#pragma unroll 4
        for (int k = 0; k < 16; k++) {
            float4 xv = *(const float4*)&xs_t[(kb + k) * 32 + r0];
#pragma unroll
            for (int h = 0; h < 4; h++) {
                float2 w = wsh2[k * 128 + h * 32 + da2];
                acc[0][2*h] += xv.x * w.x; acc[0][2*h+1] += xv.x * w.y;
                acc[1][2*h] += xv.y * w.x; acc[1][2*h+1] += xv.y * w.y;
                acc[2][2*h] += xv.z * w.x; acc[2][2*h+1] += xv.z * w.y;
                acc[3][2*h] += xv.w * w.x; acc[3][2*h+1] += xv.w * w.y;
            }
        }
    }

    // H store: fp16 dim-major; 8 halfs per row at half-offset d0*4 = 16 B
#pragma unroll
    for (int i = 0; i < 4; i++) {
        int n = n0 + r0 + i;
        if (n < N_NODES) {
            __half2 p[4];
            p[0] = __float22half2_rn(make_float2(acc[i][0], acc[i][2])); // d0 h0,h1
            p[1] = __float22half2_rn(make_float2(acc[i][4], acc[i][6])); // d0 h2,h3
            p[2] = __float22half2_rn(make_float2(acc[i][1], acc[i][3])); // d0+1 h0,h1
            p[3] = __float22half2_rn(make_float2(acc[i][5], acc[i][7])); // d0+1 h2,h3
            *(float4*)(H + (size_t)n * 256 + d0 * 4) = *(float4*)p;
        }
    }

    // AL: per-row per-head dot with asrc/adst, butterfly over 32-lane half
    const float2* as2 = (const float2*)asrc;
    const float2* ad2 = (const float2*)adst;
    float sp[4][4], dp[4][4];
#pragma unroll
    for (int h = 0; h < 4; h++) {
        float2 av = as2[h * 32 + da2];
        float2 dv = ad2[h * 32 + da2];
#pragma unroll
        for (int i = 0; i < 4; i++) {
            sp[i][h] = acc[i][2*h] * av.x + acc[i][2*h+1] * av.y;
            dp[i][h] = acc[i][2*h] * dv.x + acc[i][2*h+1] * dv.y;
        }
    }
#pragma unroll
    for (int o = 1; o < 32; o <<= 1) {
#pragma unroll
        for (int i = 0; i < 4; i++)
#pragma unroll
            for (int h = 0; h < 4; h++) {
                sp[i][h] += __shfl_xor(sp[i][h], o, 64);
                dp[i][h] += __shfl_xor(dp[i][h], o, 64);
            }
    }
    if (da2 == 0) {
#pragma unroll
        for (int i = 0; i < 4; i++) {
            int n = n0 + r0 + i;
            if (n < N_NODES) {
#pragma unroll
                for (int h = 0; h < 4; h++) {
                    AL[n * 8 + h]     = sp[i][h];
                    AL[n * 8 + 4 + h] = dp[i][h];
                }
            }
        }
    }
}

// ---------------- Per-destination softmax + aggregation ----------------
// One wave per dst node, single pass (no max shift; logits analytically
// bounded — validated rounds 4-7). H is fp16: lane reads 8 B (4 heads of
// dim=lane) -> per-edge fetch halves vs f32. Depth-4 load pipeline.
__global__ void __launch_bounds__(256) aggregate(
    const __half* __restrict__ H, const float* __restrict__ AL,
    const int* __restrict__ indptr, const int* __restrict__ esrc,
    const float* __restrict__ bias, float* __restrict__ XOUT) {
    int wave = threadIdx.x >> 6, lane = threadIdx.x & 63;
    int n = blockIdx.x * 4 + wave;   // 12500 * 4 == 50000 exactly

    int start = indptr[n], end = indptr[n + 1];
    const float4* AL4 = (const float4*)AL;
    const float2* H2  = (const float2*)H;    // 64 float2 per node row
    float4 ald = AL4[n * 2 + 1];

    float d0 = 0.f, d1 = 0.f, d2 = 0.f, d3 = 0.f;
    float a0 = 0.f, a1 = 0.f, a2 = 0.f, a3 = 0.f;

#define EDGE_BODY(A, Hv)                                            \
    {                                                               \
        float v0 = A.x + ald.x; v0 = fmaxf(v0, NEG_SLOPE * v0);     \
        float v1 = A.y + ald.y; v1 = fmaxf(v1, NEG_SLOPE * v1);     \
        float v2 = A.z + ald.z; v2 = fmaxf(v2, NEG_SLOPE * v2);     \
        float v3 = A.w + ald.w; v3 = fmaxf(v3, NEG_SLOPE * v3);     \
        float e0 = __expf(v0), e1 = __expf(v1);                     \
        float e2 = __expf(v2), e3 = __expf(v3);                     \
        d0 += e0; d1 += e1; d2 += e2; d3 += e3;                     \
        float2 c01 = __half22float2(((const __half2*)&Hv)[0]);      \
        float2 c23 = __half22float2(((const __half2*)&Hv)[1]);      \
        a0 += e0 * c01.x; a1 += e1 * c01.y;                         \
        a2 += e2 * c23.x; a3 += e3 * c23.y;                         \
    }

    for (int cb = start; cb < end; cb += 64) {
        int cnt = end - cb; if (cnt > 64) cnt = 64;
        int my_s = (lane < cnt) ? esrc[cb + lane] : 0;
        for (int base = 0; base < cnt; base += 4) {
            int m = cnt - base;   // wave-uniform
            int s0 = __shfl(my_s, base, 64);
            int s1 = __shfl(my_s, base + (1 < m ? 1 : 0), 64);
            int s2 = __shfl(my_s, base + (2 < m ? 2 : 0), 64);
            int s3 = __shfl(my_s, base + (3 < m ? 3 : 0), 64);
            float4 A0 = AL4[s0 * 2];
            float4 A1 = AL4[s1 * 2];
            float4 A2 = AL4[s2 * 2];
            float4 A3 = AL4[s3 * 2];
            float2 H0 = H2[(s0 << 6) + lane];
            float2 H1 = H2[(s1 << 6) + lane];
            float2 H2v = H2[(s2 << 6) + lane];
            float2 H3 = H2[(s3 << 6) + lane];
            EDGE_BODY(A0, H0);
            if (m > 1) EDGE_BODY(A1, H1);
            if (m > 2) EDGE_BODY(A2, H2v);
            if (m > 3) EDGE_BODY(A3, H3);
        }
    }
#undef EDGE_BODY

    float r = a0 / d0 + a1 / d1 + a2 / d2 + a3 / d3;
    r = 0.25f * r + bias[lane];
    r = r > 0.f ? r : (__expf(r) - 1.f);   // ELU
    XOUT[n * 64 + lane] = r;
}

// ---------------- Final FC ----------------
__global__ void __launch_bounds__(256) fc_kernel(
    const float* __restrict__ X, const float* __restrict__ fcW,
    const float* __restrict__ fcb, float* __restrict__ OUT) {
    __shared__ float ws[64 * 10];
    __shared__ float bs[10];
    int t = threadIdx.x;
    for (int i = t; i < 640; i += 256) ws[i] = fcW[i];   // 640 > blockDim
    if (t < 10) bs[t] = fcb[t];
    __syncthreads();
    int n = blockIdx.x * 256 + t;
    if (n >= N_NODES) return;
    float acc[10];
#pragma unroll
    for (int c = 0; c < 10; c++) acc[c] = bs[c];
    for (int d = 0; d < 64; d++) {
        float x = X[n * 64 + d];
#pragma unroll
        for (int c = 0; c < 10; c++) acc[c] += x * ws[d * 10 + c];
    }
#pragma unroll
    for (int c = 0; c < 10; c++) OUT[n * 10 + c] = acc[c];
}

// ---------------- Launch ----------------
extern "C" void kernel_launch(void* const* d_in, const int* in_sizes, int n_in,
                              void* d_out, int out_size, void* d_ws, size_t ws_size,
                              hipStream_t stream) {
    const float* x     = (const float*)d_in[0];
    const int*   ei    = (const int*)d_in[1];
    const float* W[3]    = {(const float*)d_in[2], (const float*)d_in[6], (const float*)d_in[10]};
    const float* asrc[3] = {(const float*)d_in[3], (const float*)d_in[7], (const float*)d_in[11]};
    const float* adst[3] = {(const float*)d_in[4], (const float*)d_in[8], (const float*)d_in[12]};
    const float* bias[3] = {(const float*)d_in[5], (const float*)d_in[9], (const float*)d_in[13]};
    const float* fcW = (const float*)d_in[14];
    const float* fcb = (const float*)d_in[15];
    float* out = (float*)d_out;

    char* ws = (char*)d_ws;
    size_t off = 0;
    auto alloc = [&](size_t bytes) {
        void* p = ws + off;
        off = (off + bytes + 255) & ~(size_t)255;
        return p;
    };
    __half* H     = (__half*)alloc((size_t)N_NODES * 256 * 2);  // 25.6 MB fp16
    float* AL     = (float*)alloc((size_t)N_NODES * 8 * 4);     // 1.6 MB
    float* XA     = (float*)alloc((size_t)N_NODES * 64 * 4);    // 12.8 MB
    float* XB     = (float*)alloc((size_t)N_NODES * 64 * 4);    // 12.8 MB
    int*   counts = (int*)alloc((size_t)N_NODES * 4);
    int*   indptr = (int*)alloc((size_t)(N_NODES + 1) * 4);
    int*   cursor = (int*)alloc((size_t)N_NODES * 4);
    int*   esrc   = (int*)alloc((size_t)E_TOT * 4);             // 3.4 MB
    int*   bsums  = (int*)alloc(256 * 4);
    int*   flag   = (int*)alloc(256 * 4);

    // CSR build (graph is identical each call; ws is re-poisoned so rebuild)
    zero_counts<<<NB_SCAN, 256, 0, stream>>>(counts, flag);
    detect_i32<<<1, 256, 0, stream>>>(ei, flag);
    count_edges<<<NB_EDGE, 256, 0, stream>>>(ei, counts, flag);
    scan1<<<NB_SCAN, 256, 0, stream>>>(counts, indptr, bsums);
    scan2<<<1, 256, 0, stream>>>(bsums);
    scan3<<<NB_SCAN, 256, 0, stream>>>(indptr, bsums, cursor);
    fill_edges<<<NB_EDGE, 256, 0, stream>>>(ei, cursor, esrc, flag);

    // Layer 0
    gemm_al<128><<<NB_GEMM, 256, 0, stream>>>(x, W[0], asrc[0], adst[0], H, AL);
    aggregate<<<N_NODES / 4, 256, 0, stream>>>(H, AL, indptr, esrc, bias[0], XA);
    // Layer 1
    gemm_al<64><<<NB_GEMM, 256, 0, stream>>>(XA, W[1], asrc[1], adst[1], H, AL);
    aggregate<<<N_NODES / 4, 256, 0, stream>>>(H, AL, indptr, esrc, bias[1], XB);
    // Layer 2
    gemm_al<64><<<NB_GEMM, 256, 0, stream>>>(XB, W[2], asrc[2], adst[2], H, AL);
    aggregate<<<N_NODES / 4, 256, 0, stream>>>(H, AL, indptr, esrc, bias[2], XA);

    // Final FC
    fc_kernel<<<NB_SCAN, 256, 0, stream>>>(XA, fcW, fcb, out);
}

// Round 9
// 557.570 us; speedup vs baseline: 1.4693x; 1.0381x over previous
//
#include <hip/hip_runtime.h>
#include <hip/hip_fp16.h>
#include <math.h>

// Problem constants (from reference)
#define N_NODES 50000
#define IN_DIM  128
#define HIDDEN  64
#define OUT_DIM 10
#define HEADS   4
#define E_RAW   800000
#define E_TOT   (E_RAW + N_NODES)   // with self-loops: 850000
#define NEG_SLOPE 0.2f

#define NB_SCAN 196   // ceil(50000/256)
#define NB_EDGE 3321  // ceil(850000/256)
#define NB_GEMM 782   // ceil(50000/64)

// ---------------- edge_index dtype detection ----------------
// flag[0] == 1  =>  int32 layout (shift 0);  flag[0] == 0  =>  int64 (shift 1).
__global__ void detect_i32(const int* __restrict__ ei, int* __restrict__ flag) {
    int t = threadIdx.x;                      // single block of 256
    int idx = 2 * (t * 3100 + 17) + 1;        // odd, < 1.6M for t < 256
    if (ei[idx] != 0) atomicOr(flag, 1);
}

// ---------------- CSR build ----------------

__global__ void zero_counts(int* __restrict__ counts, int* __restrict__ flag) {
    int i = blockIdx.x * 256 + threadIdx.x;
    if (i < N_NODES) counts[i] = 0;
    if (i == 0) flag[0] = 0;
}

__global__ void count_edges(const int* __restrict__ ei, int* __restrict__ counts,
                            const int* __restrict__ flag) {
    int t = blockIdx.x * 256 + threadIdx.x;
    if (t >= E_TOT) return;
    int sh = flag[0] ? 0 : 1;                 // int32 -> 0, int64 -> 1 (low word)
    int dst = (t < E_RAW) ? ei[(E_RAW + t) << sh] : (t - E_RAW);
    atomicAdd(&counts[dst], 1);
}

__global__ void scan1(const int* __restrict__ counts, int* __restrict__ indptr,
                      int* __restrict__ bsums) {
    __shared__ int sd[256];
    int t = threadIdx.x;
    int i = blockIdx.x * 256 + t;
    int v = (i < N_NODES) ? counts[i] : 0;
    sd[t] = v;
    __syncthreads();
    for (int o = 1; o < 256; o <<= 1) {
        int x = (t >= o) ? sd[t - o] : 0;
        __syncthreads();
        sd[t] += x;
        __syncthreads();
    }
    int incl = sd[t];
    if (i < N_NODES) indptr[i] = incl - v;   // block-local exclusive
    if (t == 255) bsums[blockIdx.x] = incl;  // block total
}

__global__ void scan2(int* __restrict__ bsums) {
    __shared__ int sd[256];
    int t = threadIdx.x;
    int v = (t < NB_SCAN) ? bsums[t] : 0;
    sd[t] = v;
    __syncthreads();
    for (int o = 1; o < 256; o <<= 1) {
        int x = (t >= o) ? sd[t - o] : 0;
        __syncthreads();
        sd[t] += x;
        __syncthreads();
    }
    if (t < NB_SCAN) bsums[t] = sd[t] - v;   // exclusive block offsets
}

__global__ void scan3(int* __restrict__ indptr, const int* __restrict__ bsums,
                      int* __restrict__ cursor) {
    int i = blockIdx.x * 256 + threadIdx.x;
    if (i < N_NODES) {
        int v = indptr[i] + bsums[blockIdx.x];
        indptr[i] = v;
        cursor[i] = v;
    }
    if (i == 0) indptr[N_NODES] = E_TOT;
}

__global__ void fill_edges(const int* __restrict__ ei, int* __restrict__ cursor,
                           int* __restrict__ esrc, const int* __restrict__ flag) {
    int t = blockIdx.x * 256 + threadIdx.x;
    if (t >= E_TOT) return;
    int sh = flag[0] ? 0 : 1;
    int src, dst;
    if (t < E_RAW) { src = ei[t << sh]; dst = ei[(E_RAW + t) << sh]; }
    else           { src = t - E_RAW; dst = src; }
    int pos = atomicAdd(&cursor[dst], 1);
    esrc[pos] = src;
}

// ---------------- GEMM + attention logits (64-row tile, LDS-balanced) ------
// Tile: 64 rows x 256 cols per 256-thread block; thread (da2=t&31, rg=t>>5)
// owns rows rg*8..+7 and cols {h*64 + da2*2 +0,1 : h} -> acc[8][8].
// Per k: 2 ds_read_b128 (x, broadcast) + 4 ds_read_b64 (w, 2-way = free)
// feed 64 FMA-instr -> LDS:VALU = 1:1 per CU (was 1.5:1 LDS-bound in r8).
// Staging is conflict-free: X scatter lane=row (consecutive dwords), W copy
// straight float4. k processed in 32-chunks: LDS = 8 KB (xs) + 32 KB (wsh).
// H stored DIM-MAJOR FP16: H[n*256 + d*4 + h]; 8 halfs/row = one 16 B store.
template <int K>
__global__ void __launch_bounds__(256) gemm_al(
    const float* __restrict__ X, const float* __restrict__ W,
    const float* __restrict__ asrc, const float* __restrict__ adst,
    __half* __restrict__ H, float* __restrict__ AL) {
    __shared__ float xs_t[32 * 64];     // [k-in-chunk][row]
    __shared__ float wsh[32 * 256];     // one 32-k chunk of W
    int t = threadIdx.x;
    int n0 = blockIdx.x * 64;

    int da2 = t & 31;          // dim pair: d0 = da2*2
    int rg  = t >> 5;          // row group: r0 = rg*8
    int d0 = da2 * 2;
    int r0 = rg * 8;

    float acc[8][8];
#pragma unroll
    for (int i = 0; i < 8; i++)
#pragma unroll
        for (int j = 0; j < 8; j++) acc[i][j] = 0.f;

    const int K4 = K / 4;
    const float4* X4 = (const float4*)X;
    float4* xs4 = (float4*)xs_t;        // unused alias (keeps types close)
    (void)xs4;
    float4* wsh4 = (float4*)wsh;
    const float2* wsh2 = (const float2*)wsh;

    int xr = t & 63;                    // staging row for this thread
    int xj = t >> 6;                    // staging k4-slot (0..3) per chunk
    int xn = n0 + xr; if (xn >= N_NODES) xn = N_NODES - 1;

    for (int kb = 0; kb < K; kb += 32) {
        __syncthreads();   // previous chunk consumed
        // stage X chunk transposed: 64 rows x 32 k; thread loads 2 float4
        // (k4-slots xj, xj+4) from row xr, scatters b32 lane=row (no conflict)
#pragma unroll
        for (int c = 0; c < 2; c++) {
            int k4 = xj + 4 * c;        // 0..7 within chunk
            float4 v = X4[(size_t)xn * K4 + (kb >> 2) + k4];
            xs_t[(4 * k4 + 0) * 64 + xr] = v.x;
            xs_t[(4 * k4 + 1) * 64 + xr] = v.y;
            xs_t[(4 * k4 + 2) * 64 + xr] = v.z;
            xs_t[(4 * k4 + 3) * 64 + xr] = v.w;
        }
        // stage W chunk: 32 x 256 floats = 2048 float4, 8 per thread
        const float4* Wc = (const float4*)(W + kb * 256);
#pragma unroll
        for (int m = 0; m < 8; m++) wsh4[t + 256 * m] = Wc[t + 256 * m];
        __syncthreads();

#pragma unroll 4
        for (int k = 0; k < 32; k++) {
            float4 xa = *(const float4*)&xs_t[k * 64 + r0];
            float4 xb = *(const float4*)&xs_t[k * 64 + r0 + 4];
#pragma unroll
            for (int h = 0; h < 4; h++) {
                float2 w = wsh2[k * 128 + h * 32 + da2];
                acc[0][2*h] += xa.x * w.x; acc[0][2*h+1] += xa.x * w.y;
                acc[1][2*h] += xa.y * w.x; acc[1][2*h+1] += xa.y * w.y;
                acc[2][2*h] += xa.z * w.x; acc[2][2*h+1] += xa.z * w.y;
                acc[3][2*h] += xa.w * w.x; acc[3][2*h+1] += xa.w * w.y;
                acc[4][2*h] += xb.x * w.x; acc[4][2*h+1] += xb.x * w.y;
                acc[5][2*h] += xb.y * w.x; acc[5][2*h+1] += xb.y * w.y;
                acc[6][2*h] += xb.z * w.x; acc[6][2*h+1] += xb.z * w.y;
                acc[7][2*h] += xb.w * w.x; acc[7][2*h+1] += xb.w * w.y;
            }
        }
    }

    // H store: fp16 dim-major; 8 halfs per row at half-offset d0*4 = 16 B
#pragma unroll
    for (int i = 0; i < 8; i++) {
        int n = n0 + r0 + i;
        if (n < N_NODES) {
            __half2 p[4];
            p[0] = __float22half2_rn(make_float2(acc[i][0], acc[i][2])); // d0 h0,h1
            p[1] = __float22half2_rn(make_float2(acc[i][4], acc[i][6])); // d0 h2,h3
            p[2] = __float22half2_rn(make_float2(acc[i][1], acc[i][3])); // d0+1 h0,h1
            p[3] = __float22half2_rn(make_float2(acc[i][5], acc[i][7])); // d0+1 h2,h3
            *(float4*)(H + (size_t)n * 256 + d0 * 4) = *(float4*)p;
        }
    }

    // AL: per-row per-head dot with asrc/adst, butterfly over 32-lane half.
    // Done in two 4-row halves to cap live registers.
    const float2* as2 = (const float2*)asrc;
    const float2* ad2 = (const float2*)adst;
#pragma unroll
    for (int half = 0; half < 2; half++) {
        float sp[4][4], dp[4][4];
#pragma unroll
        for (int h = 0; h < 4; h++) {
            float2 av = as2[h * 32 + da2];
            float2 dv = ad2[h * 32 + da2];
#pragma unroll
            for (int ii = 0; ii < 4; ii++) {
                int i = half * 4 + ii;
                sp[ii][h] = acc[i][2*h] * av.x + acc[i][2*h+1] * av.y;
                dp[ii][h] = acc[i][2*h] * dv.x + acc[i][2*h+1] * dv.y;
            }
        }
#pragma unroll
        for (int o = 1; o < 32; o <<= 1) {
#pragma unroll
            for (int ii = 0; ii < 4; ii++)
#pragma unroll
                for (int h = 0; h < 4; h++) {
                    sp[ii][h] += __shfl_xor(sp[ii][h], o, 64);
                    dp[ii][h] += __shfl_xor(dp[ii][h], o, 64);
                }
        }
        if (da2 == 0) {
#pragma unroll
            for (int ii = 0; ii < 4; ii++) {
                int n = n0 + r0 + half * 4 + ii;
                if (n < N_NODES) {
#pragma unroll
                    for (int h = 0; h < 4; h++) {
                        AL[n * 8 + h]     = sp[ii][h];
                        AL[n * 8 + 4 + h] = dp[ii][h];
                    }
                }
            }
        }
    }
}

// ---------------- Per-destination softmax + aggregation ----------------
// One wave per dst node, single pass (no max shift; logits analytically
// bounded — validated rounds 4-8). H is fp16: lane reads 8 B (4 heads of
// dim=lane). Depth-4 load pipeline. Fetch-bound at the L2-miss path
// (~3.6 TB/s observed); bytes are near the reuse floor — leave as-is.
__global__ void __launch_bounds__(256) aggregate(
    const __half* __restrict__ H, const float* __restrict__ AL,
    const int* __restrict__ indptr, const int* __restrict__ esrc,
    const float* __restrict__ bias, float* __restrict__ XOUT) {
    int wave = threadIdx.x >> 6, lane = threadIdx.x & 63;
    int n = blockIdx.x * 4 + wave;   // 12500 * 4 == 50000 exactly

    int start = indptr[n], end = indptr[n + 1];
    const float4* AL4 = (const float4*)AL;
    const float2* H2  = (const float2*)H;    // 64 float2 per node row
    float4 ald = AL4[n * 2 + 1];

    float d0 = 0.f, d1 = 0.f, d2 = 0.f, d3 = 0.f;
    float a0 = 0.f, a1 = 0.f, a2 = 0.f, a3 = 0.f;

#define EDGE_BODY(A, Hv)                                            \
    {                                                               \
        float v0 = A.x + ald.x; v0 = fmaxf(v0, NEG_SLOPE * v0);     \
        float v1 = A.y + ald.y; v1 = fmaxf(v1, NEG_SLOPE * v1);     \
        float v2 = A.z + ald.z; v2 = fmaxf(v2, NEG_SLOPE * v2);     \
        float v3 = A.w + ald.w; v3 = fmaxf(v3, NEG_SLOPE * v3);     \
        float e0 = __expf(v0), e1 = __expf(v1);                     \
        float e2 = __expf(v2), e3 = __expf(v3);                     \
        d0 += e0; d1 += e1; d2 += e2; d3 += e3;                     \
        float2 c01 = __half22float2(((const __half2*)&Hv)[0]);      \
        float2 c23 = __half22float2(((const __half2*)&Hv)[1]);      \
        a0 += e0 * c01.x; a1 += e1 * c01.y;                         \
        a2 += e2 * c23.x; a3 += e3 * c23.y;                         \
    }

    for (int cb = start; cb < end; cb += 64) {
        int cnt = end - cb; if (cnt > 64) cnt = 64;
        int my_s = (lane < cnt) ? esrc[cb + lane] : 0;
        for (int base = 0; base < cnt; base += 4) {
            int m = cnt - base;   // wave-uniform
            int s0 = __shfl(my_s, base, 64);
            int s1 = __shfl(my_s, base + (1 < m ? 1 : 0), 64);
            int s2 = __shfl(my_s, base + (2 < m ? 2 : 0), 64);
            int s3 = __shfl(my_s, base + (3 < m ? 3 : 0), 64);
            float4 A0 = AL4[s0 * 2];
            float4 A1 = AL4[s1 * 2];
            float4 A2 = AL4[s2 * 2];
            float4 A3 = AL4[s3 * 2];
            float2 H0 = H2[(s0 << 6) + lane];
            float2 H1 = H2[(s1 << 6) + lane];
            float2 H2v = H2[(s2 << 6) + lane];
            float2 H3 = H2[(s3 << 6) + lane];
            EDGE_BODY(A0, H0);
            if (m > 1) EDGE_BODY(A1, H1);
            if (m > 2) EDGE_BODY(A2, H2v);
            if (m > 3) EDGE_BODY(A3, H3);
        }
    }
#undef EDGE_BODY

    float r = a0 / d0 + a1 / d1 + a2 / d2 + a3 / d3;
    r = 0.25f * r + bias[lane];
    r = r > 0.f ? r : (__expf(r) - 1.f);   // ELU
    XOUT[n * 64 + lane] = r;
}

// ---------------- Final FC ----------------
__global__ void __launch_bounds__(256) fc_kernel(
    const float* __restrict__ X, const float* __restrict__ fcW,
    const float* __restrict__ fcb, float* __restrict__ OUT) {
    __shared__ float ws[64 * 10];
    __shared__ float bs[10];
    int t = threadIdx.x;
    for (int i = t; i < 640; i += 256) ws[i] = fcW[i];   // 640 > blockDim
    if (t < 10) bs[t] = fcb[t];
    __syncthreads();
    int n = blockIdx.x * 256 + t;
    if (n >= N_NODES) return;
    float acc[10];
#pragma unroll
    for (int c = 0; c < 10; c++) acc[c] = bs[c];
    for (int d = 0; d < 64; d++) {
        float x = X[n * 64 + d];
#pragma unroll
        for (int c = 0; c < 10; c++) acc[c] += x * ws[d * 10 + c];
    }
#pragma unroll
    for (int c = 0; c < 10; c++) OUT[n * 10 + c] = acc[c];
}

// ---------------- Launch ----------------
extern "C" void kernel_launch(void* const* d_in, const int* in_sizes, int n_in,
                              void* d_out, int out_size, void* d_ws, size_t ws_size,
                              hipStream_t stream) {
    const float* x     = (const float*)d_in[0];
    const int*   ei    = (const int*)d_in[1];
    const float* W[3]    = {(const float*)d_in[2], (const float*)d_in[6], (const float*)d_in[10]};
    const float* asrc[3] = {(const float*)d_in[3], (const float*)d_in[7], (const float*)d_in[11]};
    const float* adst[3] = {(const float*)d_in[4], (const float*)d_in[8], (const float*)d_in[12]};
    const float* bias[3] = {(const float*)d_in[5], (const float*)d_in[9], (const float*)d_in[13]};
    const float* fcW = (const float*)d_in[14];
    const float* fcb = (const float*)d_in[15];
    float* out = (float*)d_out;

    char* ws = (char*)d_ws;
    size_t off = 0;
    auto alloc = [&](size_t bytes) {
        void* p = ws + off;
        off = (off + bytes + 255) & ~(size_t)255;
        return p;
    };
    __half* H     = (__half*)alloc((size_t)N_NODES * 256 * 2);  // 25.6 MB fp16
    float* AL     = (float*)alloc((size_t)N_NODES * 8 * 4);     // 1.6 MB
    float* XA     = (float*)alloc((size_t)N_NODES * 64 * 4);    // 12.8 MB
    float* XB     = (float*)alloc((size_t)N_NODES * 64 * 4);    // 12.8 MB
    int*   counts = (int*)alloc((size_t)N_NODES * 4);
    int*   indptr = (int*)alloc((size_t)(N_NODES + 1) * 4);
    int*   cursor = (int*)alloc((size_t)N_NODES * 4);
    int*   esrc   = (int*)alloc((size_t)E_TOT * 4);             // 3.4 MB
    int*   bsums  = (int*)alloc(256 * 4);
    int*   flag   = (int*)alloc(256 * 4);

    // CSR build (graph is identical each call; ws is re-poisoned so rebuild)
    zero_counts<<<NB_SCAN, 256, 0, stream>>>(counts, flag);
    detect_i32<<<1, 256, 0, stream>>>(ei, flag);
    count_edges<<<NB_EDGE, 256, 0, stream>>>(ei, counts, flag);
    scan1<<<NB_SCAN, 256, 0, stream>>>(counts, indptr, bsums);
    scan2<<<1, 256, 0, stream>>>(bsums);
    scan3<<<NB_SCAN, 256, 0, stream>>>(indptr, bsums, cursor);
    fill_edges<<<NB_EDGE, 256, 0, stream>>>(ei, cursor, esrc, flag);

    // Layer 0
    gemm_al<128><<<NB_GEMM, 256, 0, stream>>>(x, W[0], asrc[0], adst[0], H, AL);
    aggregate<<<N_NODES / 4, 256, 0, stream>>>(H, AL, indptr, esrc, bias[0], XA);
    // Layer 1
    gemm_al<64><<<NB_GEMM, 256, 0, stream>>>(XA, W[1], asrc[1], adst[1], H, AL);
    aggregate<<<N_NODES / 4, 256, 0, stream>>>(H, AL, indptr, esrc, bias[1], XB);
    // Layer 2
    gemm_al<64><<<NB_GEMM, 256, 0, stream>>>(XB, W[2], asrc[2], adst[2], H, AL);
    aggregate<<<N_NODES / 4, 256, 0, stream>>>(H, AL, indptr, esrc, bias[2], XA);

    // Final FC
    fc_kernel<<<NB_SCAN, 256, 0, stream>>>(XA, fcW, fcb, out);
}

// Round 10
// 551.849 us; speedup vs baseline: 1.4845x; 1.0104x over previous
//
#include <hip/hip_runtime.h>
#include <hip/hip_fp16.h>
#include <math.h>

// Problem constants (from reference)
#define N_NODES 50000
#define IN_DIM  128
#define HIDDEN  64
#define OUT_DIM 10
#define HEADS   4
#define E_RAW   800000
#define E_TOT   (E_RAW + N_NODES)   // with self-loops: 850000
#define NEG_SLOPE 0.2f

#define NB_SCAN 196   // ceil(50000/256)
#define NB_EDGE 3321  // ceil(850000/256)
#define NB_GEMM 782   // ceil(50000/64)

// ---------------- edge_index dtype detection ----------------
// flag[0] == 1  =>  int32 layout (shift 0);  flag[0] == 0  =>  int64 (shift 1).
__global__ void detect_i32(const int* __restrict__ ei, int* __restrict__ flag) {
    int t = threadIdx.x;                      // single block of 256
    int idx = 2 * (t * 3100 + 17) + 1;        // odd, < 1.6M for t < 256
    if (ei[idx] != 0) atomicOr(flag, 1);
}

// ---------------- CSR build ----------------

__global__ void zero_counts(int* __restrict__ counts, int* __restrict__ flag) {
    int i = blockIdx.x * 256 + threadIdx.x;
    if (i < N_NODES) counts[i] = 0;
    if (i == 0) flag[0] = 0;
}

__global__ void count_edges(const int* __restrict__ ei, int* __restrict__ counts,
                            const int* __restrict__ flag) {
    int t = blockIdx.x * 256 + threadIdx.x;
    if (t >= E_TOT) return;
    int sh = flag[0] ? 0 : 1;                 // int32 -> 0, int64 -> 1 (low word)
    int dst = (t < E_RAW) ? ei[(E_RAW + t) << sh] : (t - E_RAW);
    atomicAdd(&counts[dst], 1);
}

__global__ void scan1(const int* __restrict__ counts, int* __restrict__ indptr,
                      int* __restrict__ bsums) {
    __shared__ int sd[256];
    int t = threadIdx.x;
    int i = blockIdx.x * 256 + t;
    int v = (i < N_NODES) ? counts[i] : 0;
    sd[t] = v;
    __syncthreads();
    for (int o = 1; o < 256; o <<= 1) {
        int x = (t >= o) ? sd[t - o] : 0;
        __syncthreads();
        sd[t] += x;
        __syncthreads();
    }
    int incl = sd[t];
    if (i < N_NODES) indptr[i] = incl - v;   // block-local exclusive
    if (t == 255) bsums[blockIdx.x] = incl;  // block total
}

__global__ void scan2(int* __restrict__ bsums) {
    __shared__ int sd[256];
    int t = threadIdx.x;
    int v = (t < NB_SCAN) ? bsums[t] : 0;
    sd[t] = v;
    __syncthreads();
    for (int o = 1; o < 256; o <<= 1) {
        int x = (t >= o) ? sd[t - o] : 0;
        __syncthreads();
        sd[t] += x;
        __syncthreads();
    }
    if (t < NB_SCAN) bsums[t] = sd[t] - v;   // exclusive block offsets
}

__global__ void scan3(int* __restrict__ indptr, const int* __restrict__ bsums,
                      int* __restrict__ cursor) {
    int i = blockIdx.x * 256 + threadIdx.x;
    if (i < N_NODES) {
        int v = indptr[i] + bsums[blockIdx.x];
        indptr[i] = v;
        cursor[i] = v;
    }
    if (i == 0) indptr[N_NODES] = E_TOT;
}

__global__ void fill_edges(const int* __restrict__ ei, int* __restrict__ cursor,
                           int* __restrict__ esrc, int* __restrict__ edst,
                           const int* __restrict__ flag) {
    int t = blockIdx.x * 256 + threadIdx.x;
    if (t >= E_TOT) return;
    int sh = flag[0] ? 0 : 1;
    int src, dst;
    if (t < E_RAW) { src = ei[t << sh]; dst = ei[(E_RAW + t) << sh]; }
    else           { src = t - E_RAW; dst = src; }
    int pos = atomicAdd(&cursor[dst], 1);
    esrc[pos] = src;
    edst[pos] = dst;
}

// ---------------- GEMM + attention logits (64-row tile, LDS-balanced) ------
// (unchanged from round 9 — conflict-free staging, LDS:VALU ~1:1)
template <int K>
__global__ void __launch_bounds__(256) gemm_al(
    const float* __restrict__ X, const float* __restrict__ W,
    const float* __restrict__ asrc, const float* __restrict__ adst,
    __half* __restrict__ H, float* __restrict__ AL) {
    __shared__ float xs_t[32 * 64];     // [k-in-chunk][row]
    __shared__ float wsh[32 * 256];     // one 32-k chunk of W
    int t = threadIdx.x;
    int n0 = blockIdx.x * 64;

    int da2 = t & 31;          // dim pair: d0 = da2*2
    int rg  = t >> 5;          // row group: r0 = rg*8
    int d0 = da2 * 2;
    int r0 = rg * 8;

    float acc[8][8];
#pragma unroll
    for (int i = 0; i < 8; i++)
#pragma unroll
        for (int j = 0; j < 8; j++) acc[i][j] = 0.f;

    const int K4 = K / 4;
    const float4* X4 = (const float4*)X;
    float4* wsh4 = (float4*)wsh;
    const float2* wsh2 = (const float2*)wsh;

    int xr = t & 63;                    // staging row for this thread
    int xj = t >> 6;                    // staging k4-slot (0..3) per chunk
    int xn = n0 + xr; if (xn >= N_NODES) xn = N_NODES - 1;

    for (int kb = 0; kb < K; kb += 32) {
        __syncthreads();   // previous chunk consumed
#pragma unroll
        for (int c = 0; c < 2; c++) {
            int k4 = xj + 4 * c;        // 0..7 within chunk
            float4 v = X4[(size_t)xn * K4 + (kb >> 2) + k4];
            xs_t[(4 * k4 + 0) * 64 + xr] = v.x;
            xs_t[(4 * k4 + 1) * 64 + xr] = v.y;
            xs_t[(4 * k4 + 2) * 64 + xr] = v.z;
            xs_t[(4 * k4 + 3) * 64 + xr] = v.w;
        }
        const float4* Wc = (const float4*)(W + kb * 256);
#pragma unroll
        for (int m = 0; m < 8; m++) wsh4[t + 256 * m] = Wc[t + 256 * m];
        __syncthreads();

#pragma unroll 4
        for (int k = 0; k < 32; k++) {
            float4 xa = *(const float4*)&xs_t[k * 64 + r0];
            float4 xb = *(const float4*)&xs_t[k * 64 + r0 + 4];
#pragma unroll
            for (int h = 0; h < 4; h++) {
                float2 w = wsh2[k * 128 + h * 32 + da2];
                acc[0][2*h] += xa.x * w.x; acc[0][2*h+1] += xa.x * w.y;
                acc[1][2*h] += xa.y * w.x; acc[1][2*h+1] += xa.y * w.y;
                acc[2][2*h] += xa.z * w.x; acc[2][2*h+1] += xa.z * w.y;
                acc[3][2*h] += xa.w * w.x; acc[3][2*h+1] += xa.w * w.y;
                acc[4][2*h] += xb.x * w.x; acc[4][2*h+1] += xb.x * w.y;
                acc[5][2*h] += xb.y * w.x; acc[5][2*h+1] += xb.y * w.y;
                acc[6][2*h] += xb.z * w.x; acc[6][2*h+1] += xb.z * w.y;
                acc[7][2*h] += xb.w * w.x; acc[7][2*h+1] += xb.w * w.y;
            }
        }
    }

    // H store: fp16 dim-major; 8 halfs per row at half-offset d0*4 = 16 B
#pragma unroll
    for (int i = 0; i < 8; i++) {
        int n = n0 + r0 + i;
        if (n < N_NODES) {
            __half2 p[4];
            p[0] = __float22half2_rn(make_float2(acc[i][0], acc[i][2])); // d0 h0,h1
            p[1] = __float22half2_rn(make_float2(acc[i][4], acc[i][6])); // d0 h2,h3
            p[2] = __float22half2_rn(make_float2(acc[i][1], acc[i][3])); // d0+1 h0,h1
            p[3] = __float22half2_rn(make_float2(acc[i][5], acc[i][7])); // d0+1 h2,h3
            *(float4*)(H + (size_t)n * 256 + d0 * 4) = *(float4*)p;
        }
    }

    // AL: per-row per-head dot with asrc/adst, butterfly over 32-lane half.
    const float2* as2 = (const float2*)asrc;
    const float2* ad2 = (const float2*)adst;
#pragma unroll
    for (int half = 0; half < 2; half++) {
        float sp[4][4], dp[4][4];
#pragma unroll
        for (int h = 0; h < 4; h++) {
            float2 av = as2[h * 32 + da2];
            float2 dv = ad2[h * 32 + da2];
#pragma unroll
            for (int ii = 0; ii < 4; ii++) {
                int i = half * 4 + ii;
                sp[ii][h] = acc[i][2*h] * av.x + acc[i][2*h+1] * av.y;
                dp[ii][h] = acc[i][2*h] * dv.x + acc[i][2*h+1] * dv.y;
            }
        }
#pragma unroll
        for (int o = 1; o < 32; o <<= 1) {
#pragma unroll
            for (int ii = 0; ii < 4; ii++)
#pragma unroll
                for (int h = 0; h < 4; h++) {
                    sp[ii][h] += __shfl_xor(sp[ii][h], o, 64);
                    dp[ii][h] += __shfl_xor(dp[ii][h], o, 64);
                }
        }
        if (da2 == 0) {
#pragma unroll
            for (int ii = 0; ii < 4; ii++) {
                int n = n0 + r0 + half * 4 + ii;
                if (n < N_NODES) {
#pragma unroll
                    for (int h = 0; h < 4; h++) {
                        AL[n * 8 + h]     = sp[ii][h];
                        AL[n * 8 + 4 + h] = dp[ii][h];
                    }
                }
            }
        }
    }
}

// ---------------- Per-edge unnormalized attention weights ----------------
// One thread per CSR edge position. Hoists the math that aggregate used to
// replicate across all 64 lanes: EW[p] = exp(leaky(AL_src + AL_dst)) per head.
// No max shift: logits analytically bounded (validated rounds 4-9); f32 exp.
__global__ void __launch_bounds__(256) edge_weights(
    const float* __restrict__ AL, const int* __restrict__ esrc,
    const int* __restrict__ edst, float4* __restrict__ EW) {
    int p = blockIdx.x * 256 + threadIdx.x;
    if (p >= E_TOT) return;
    int s = esrc[p], d = edst[p];
    const float4* AL4 = (const float4*)AL;
    float4 as = AL4[s * 2];        // src logits (4 heads)
    float4 ad = AL4[d * 2 + 1];    // dst logits (4 heads)
    float v0 = as.x + ad.x; v0 = fmaxf(v0, NEG_SLOPE * v0);
    float v1 = as.y + ad.y; v1 = fmaxf(v1, NEG_SLOPE * v1);
    float v2 = as.z + ad.z; v2 = fmaxf(v2, NEG_SLOPE * v2);
    float v3 = as.w + ad.w; v3 = fmaxf(v3, NEG_SLOPE * v3);
    EW[p] = make_float4(__expf(v0), __expf(v1), __expf(v2), __expf(v3));
}

// ---------------- Per-destination aggregation ----------------
// One wave per dst node. Per edge: one wave-uniform 16 B EW broadcast load
// + one 8 B H gather per lane + 4 FMA / 4 add. The exp/leaky math lives in
// edge_weights now (it was replicated 64x per lane before — r9 VALUBusy 84%).
__global__ void __launch_bounds__(256) aggregate(
    const __half* __restrict__ H, const float4* __restrict__ EW,
    const int* __restrict__ indptr, const int* __restrict__ esrc,
    const float* __restrict__ bias, float* __restrict__ XOUT) {
    int wave = threadIdx.x >> 6, lane = threadIdx.x & 63;
    int n = blockIdx.x * 4 + wave;   // 12500 * 4 == 50000 exactly

    int start = indptr[n], end = indptr[n + 1];
    const float2* H2 = (const float2*)H;    // 64 float2 per node row

    float d0 = 0.f, d1 = 0.f, d2 = 0.f, d3 = 0.f;
    float a0 = 0.f, a1 = 0.f, a2 = 0.f, a3 = 0.f;

#define EDGE_BODY(E, Hv)                                            \
    {                                                               \
        d0 += E.x; d1 += E.y; d2 += E.z; d3 += E.w;                 \
        float2 c01 = __half22float2(((const __half2*)&Hv)[0]);      \
        float2 c23 = __half22float2(((const __half2*)&Hv)[1]);      \
        a0 += E.x * c01.x; a1 += E.y * c01.y;                       \
        a2 += E.z * c23.x; a3 += E.w * c23.y;                       \
    }

    for (int cb = start; cb < end; cb += 64) {
        int cnt = end - cb; if (cnt > 64) cnt = 64;
        int my_s = (lane < cnt) ? esrc[cb + lane] : 0;
        for (int base = 0; base < cnt; base += 4) {
            int m = cnt - base;   // wave-uniform
            int s0 = __shfl(my_s, base, 64);
            int s1 = __shfl(my_s, base + (1 < m ? 1 : 0), 64);
            int s2 = __shfl(my_s, base + (2 < m ? 2 : 0), 64);
            int s3 = __shfl(my_s, base + (3 < m ? 3 : 0), 64);
            float4 E0 = EW[cb + base];                       // uniform -> bcast
            float4 E1 = EW[cb + base + (1 < m ? 1 : 0)];
            float4 E2 = EW[cb + base + (2 < m ? 2 : 0)];
            float4 E3 = EW[cb + base + (3 < m ? 3 : 0)];
            float2 H0 = H2[(s0 << 6) + lane];
            float2 H1 = H2[(s1 << 6) + lane];
            float2 H2v = H2[(s2 << 6) + lane];
            float2 H3 = H2[(s3 << 6) + lane];
            EDGE_BODY(E0, H0);
            if (m > 1) EDGE_BODY(E1, H1);
            if (m > 2) EDGE_BODY(E2, H2v);
            if (m > 3) EDGE_BODY(E3, H3);
        }
    }
#undef EDGE_BODY

    float r = a0 / d0 + a1 / d1 + a2 / d2 + a3 / d3;
    r = 0.25f * r + bias[lane];
    r = r > 0.f ? r : (__expf(r) - 1.f);   // ELU
    XOUT[n * 64 + lane] = r;
}

// ---------------- Final FC ----------------
__global__ void __launch_bounds__(256) fc_kernel(
    const float* __restrict__ X, const float* __restrict__ fcW,
    const float* __restrict__ fcb, float* __restrict__ OUT) {
    __shared__ float ws[64 * 10];
    __shared__ float bs[10];
    int t = threadIdx.x;
    for (int i = t; i < 640; i += 256) ws[i] = fcW[i];   // 640 > blockDim
    if (t < 10) bs[t] = fcb[t];
    __syncthreads();
    int n = blockIdx.x * 256 + t;
    if (n >= N_NODES) return;
    float acc[10];
#pragma unroll
    for (int c = 0; c < 10; c++) acc[c] = bs[c];
    for (int d = 0; d < 64; d++) {
        float x = X[n * 64 + d];
#pragma unroll
        for (int c = 0; c < 10; c++) acc[c] += x * ws[d * 10 + c];
    }
#pragma unroll
    for (int c = 0; c < 10; c++) OUT[n * 10 + c] = acc[c];
}

// ---------------- Launch ----------------
extern "C" void kernel_launch(void* const* d_in, const int* in_sizes, int n_in,
                              void* d_out, int out_size, void* d_ws, size_t ws_size,
                              hipStream_t stream) {
    const float* x     = (const float*)d_in[0];
    const int*   ei    = (const int*)d_in[1];
    const float* W[3]    = {(const float*)d_in[2], (const float*)d_in[6], (const float*)d_in[10]};
    const float* asrc[3] = {(const float*)d_in[3], (const float*)d_in[7], (const float*)d_in[11]};
    const float* adst[3] = {(const float*)d_in[4], (const float*)d_in[8], (const float*)d_in[12]};
    const float* bias[3] = {(const float*)d_in[5], (const float*)d_in[9], (const float*)d_in[13]};
    const float* fcW = (const float*)d_in[14];
    const float* fcb = (const float*)d_in[15];
    float* out = (float*)d_out;

    char* ws = (char*)d_ws;
    size_t off = 0;
    auto alloc = [&](size_t bytes) {
        void* p = ws + off;
        off = (off + bytes + 255) & ~(size_t)255;
        return p;
    };
    __half* H     = (__half*)alloc((size_t)N_NODES * 256 * 2);  // 25.6 MB fp16
    float* AL     = (float*)alloc((size_t)N_NODES * 8 * 4);     // 1.6 MB
    float4* EW    = (float4*)alloc((size_t)E_TOT * 16);         // 13.6 MB
    float* XA     = (float*)alloc((size_t)N_NODES * 64 * 4);    // 12.8 MB
    float* XB     = (float*)alloc((size_t)N_NODES * 64 * 4);    // 12.8 MB
    int*   counts = (int*)alloc((size_t)N_NODES * 4);
    int*   indptr = (int*)alloc((size_t)(N_NODES + 1) * 4);
    int*   cursor = (int*)alloc((size_t)N_NODES * 4);
    int*   esrc   = (int*)alloc((size_t)E_TOT * 4);             // 3.4 MB
    int*   edst   = (int*)alloc((size_t)E_TOT * 4);             // 3.4 MB
    int*   bsums  = (int*)alloc(256 * 4);
    int*   flag   = (int*)alloc(256 * 4);

    // CSR build (graph is identical each call; ws is re-poisoned so rebuild)
    zero_counts<<<NB_SCAN, 256, 0, stream>>>(counts, flag);
    detect_i32<<<1, 256, 0, stream>>>(ei, flag);
    count_edges<<<NB_EDGE, 256, 0, stream>>>(ei, counts, flag);
    scan1<<<NB_SCAN, 256, 0, stream>>>(counts, indptr, bsums);
    scan2<<<1, 256, 0, stream>>>(bsums);
    scan3<<<NB_SCAN, 256, 0, stream>>>(indptr, bsums, cursor);
    fill_edges<<<NB_EDGE, 256, 0, stream>>>(ei, cursor, esrc, edst, flag);

    // Layer 0
    gemm_al<128><<<NB_GEMM, 256, 0, stream>>>(x, W[0], asrc[0], adst[0], H, AL);
    edge_weights<<<NB_EDGE, 256, 0, stream>>>(AL, esrc, edst, EW);
    aggregate<<<N_NODES / 4, 256, 0, stream>>>(H, EW, indptr, esrc, bias[0], XA);
    // Layer 1
    gemm_al<64><<<NB_GEMM, 256, 0, stream>>>(XA, W[1], asrc[1], adst[1], H, AL);
    edge_weights<<<NB_EDGE, 256, 0, stream>>>(AL, esrc, edst, EW);
    aggregate<<<N_NODES / 4, 256, 0, stream>>>(H, EW, indptr, esrc, bias[1], XB);
    // Layer 2
    gemm_al<64><<<NB_GEMM, 256, 0, stream>>>(XB, W[2], asrc[2], adst[2], H, AL);
    edge_weights<<<NB_EDGE, 256, 0, stream>>>(AL, esrc, edst, EW);
    aggregate<<<N_NODES / 4, 256, 0, stream>>>(H, EW, indptr, esrc, bias[2], XA);

    // Final FC
    fc_kernel<<<NB_SCAN, 256, 0, stream>>>(XA, fcW, fcb, out);
}